// Round 13
// baseline (338.285 us; speedup 1.0000x reference)
//
#include <hip/hip_runtime.h>
#include <float.h>

// Problem constants (B=16, N=M=4096, fp32, 3-D points)
#define BATCH  16
#define NPTS   4096
#define TOTALP (BATCH * NPTS)      // 65536 points per set
#define NQ     (2 * TOTALP)       // 131072 point slots (both sets)

typedef _Float16 half8  __attribute__((ext_vector_type(8)));
typedef float    f32x16 __attribute__((ext_vector_type(16)));

#define ONE2 0x3C003C00u          // two packed f16 1.0

// Order-preserving float->uint encode (unsigned compare == float compare).
__device__ __forceinline__ unsigned enc(float f)
{
    unsigned b = __float_as_uint(f);
    return (b & 0x80000000u) ? ~b : (b | 0x80000000u);
}
__device__ __forceinline__ float dec(unsigned k)
{
    return (k & 0x80000000u) ? __uint_as_float(k & 0x7FFFFFFFu)
                             : __uint_as_float(~k);
}

__device__ __forceinline__ unsigned pk(_Float16 lo, _Float16 hi)
{
    const unsigned a = (unsigned)__builtin_bit_cast(unsigned short, lo);
    const unsigned b = (unsigned)__builtin_bit_cast(unsigned short, hi);
    return a | (b << 16);
}

// In-register min of 16 MFMA outputs + running acc: 8 x v_min3_f32.
__device__ __forceinline__ float min16(const f32x16& d, float acc)
{
    const float m1 = fminf(fminf(d[0],  d[1]),  d[2]);
    const float m2 = fminf(fminf(d[3],  d[4]),  d[5]);
    const float m3 = fminf(fminf(d[6],  d[7]),  d[8]);
    const float m4 = fminf(fminf(d[9],  d[10]), d[11]);
    const float m5 = fminf(fminf(d[12], d[13]), d[14]);
    const float m6 = fminf(fminf(m1, m2), m3);
    const float m7 = fminf(fminf(m4, m5), d[15]);
    return fminf(fminf(m6, m7), acc);
}

// ---------------------------------------------------------------------------
// Prep kernel (512 blocks x 256): for every point i of both sets, write
//   packQ[i]   query record (u = -2x), minimal 16 B; B-frag halves are
//              {d.x,d.y,d.z,d.x} / {d.y,d.z,d.w,1|1} -> zero shuffling
//   planes[0][i] / planes[1][i]  opp record pre-expanded in MFMA A-frag
//              K-half layout -> main kernel streams them coalesced, no LDS
// Also inits keys[i] = +inf-key and out[0..1] = 0 (poisoned 0xAA).
// One K=16 f16 dot of (A-rec, B-rec) = ||x - p||^2 exactly (R8-R12 absmax=0).
// ---------------------------------------------------------------------------
__global__ __launch_bounds__(256) void prep_kernel(
    const float* __restrict__ xyz1, const float* __restrict__ xyz2,
    uint4* __restrict__ packQ, uint4* __restrict__ planes,
    unsigned* __restrict__ keys, float* __restrict__ out)
{
    const int i = blockIdx.x * 256 + threadIdx.x;    // 0..131071
    if (i == 0) { out[0] = 0.0f; out[1] = 0.0f; }
    keys[i] = 0xFFFFFFFFu;

    const float* src = (i < TOTALP) ? xyz1 : xyz2;
    const int p = i & (TOTALP - 1);
    const float x = src[3 * p + 0];
    const float y = src[3 * p + 1];
    const float z = src[3 * p + 2];
    const float sq = x * x + y * y + z * z;
    const _Float16 sh = (_Float16)sq;
    const _Float16 sl = (_Float16)(sq - (float)sh);

    // Opp-role A-fragment halves (v = x):
    //   half0 k0-7:  vxh vyh vzh vxh vyh vzh vxl vyl
    //   half1 k8-15: vzl vxl vyl vzl 1 1 sh sl
    const _Float16 vxh = (_Float16)x, vyh = (_Float16)y, vzh = (_Float16)z;
    const _Float16 vxl = (_Float16)(x - (float)vxh);
    const _Float16 vyl = (_Float16)(y - (float)vyh);
    const _Float16 vzl = (_Float16)(z - (float)vzh);
    planes[i]      = make_uint4(pk(vxh, vyh), pk(vzh, vxh),
                                pk(vyh, vzh), pk(vxl, vyl));
    planes[NQ + i] = make_uint4(pk(vzl, vxl), pk(vyl, vzl),
                                ONE2,         pk(sh, sl));

    // Query-role record (u = -2x), minimal:
    const float ux = -2.0f * x, uy = -2.0f * y, uz = -2.0f * z;
    const _Float16 uxh = (_Float16)ux, uyh = (_Float16)uy, uzh = (_Float16)uz;
    const _Float16 uxl = (_Float16)(ux - (float)uxh);
    const _Float16 uyl = (_Float16)(uy - (float)uyh);
    const _Float16 uzl = (_Float16)(uz - (float)uzh);
    packQ[i] = make_uint4(pk(uxh, uyh), pk(uzh, uxl), pk(uyl, uzl), pk(sh, sl));
}

// ---------------------------------------------------------------------------
// Q=8 MFMA chamfer. A = opp points (global, coalesced b128, ALL 8 tiles
// batch-prefetched at loop head -> compiler emits descending-vmcnt waits;
// 8 MFMA + 64 min3 of issue per load fully covers L2 latency — fixes R12's
// 1:1 MFMA:load regression). B = 8 query frags in registers (32 VGPR).
//   blk = ((dir*16 + b)*4 + qc)*16 + ch    (ALL selectors block-uniform)
//   Block: 1024 queries (4 waves x 8 frags x 32) x 256 opp points (8 tiles).
//   Grid: 2 x 16 x 4 x 16 = 2048 blocks -> 8 blocks/CU nominal.
// D layout: col(query)=lane&31, row(opp)->16 regs => min16 is in-register;
// epilogue: shfl_xor(32) merge + one atomicMin per query into keys.
// No LDS, no __syncthreads in the hot path.
// ---------------------------------------------------------------------------
__global__ __launch_bounds__(256) void chamfer_q8(
    const uint4* __restrict__ packQ, const uint4* __restrict__ planes,
    unsigned* __restrict__ keys)
{
    const int blk = blockIdx.x;
    const int ch  = blk & 15;
    const int qc  = (blk >> 4) & 3;
    const int b   = (blk >> 6) & 15;
    const int dir = blk >> 10;                   // block-uniform

    const int lane = threadIdx.x & 63;
    const int wv   = threadIdx.x >> 6;
    const int n32  = lane & 31;
    const int half = lane >> 5;

    // ---- 8 query B-fragments (zero-shuffle assembly) ----
    const int qbase = dir * TOTALP + b * NPTS + qc * 1024 + wv * 256;
    half8 bfrag[8];
#pragma unroll
    for (int qf = 0; qf < 8; ++qf) {
        const uint4 d = packQ[qbase + qf * 32 + n32];
        const uint4 u = half ? make_uint4(d.y, d.z, d.w, ONE2)
                             : make_uint4(d.x, d.y, d.z, d.x);
        bfrag[qf] = __builtin_bit_cast(half8, u);
    }

    float acc[8];
#pragma unroll
    for (int qf = 0; qf < 8; ++qf) acc[qf] = FLT_MAX;

    f32x16 cz;
#pragma unroll
    for (int r = 0; r < 16; ++r) cz[r] = 0.0f;

    // ---- batch-prefetch all 8 A-tiles (256 opp recs), coalesced b128 ----
    const uint4* __restrict__ ap =
        planes + (size_t)half * NQ + (dir ^ 1) * TOTALP + b * NPTS + ch * 256;

    uint4 tiles[8];
#pragma unroll
    for (int t = 0; t < 8; ++t)
        tiles[t] = ap[t * 32 + n32];

    // ---- compute: 8 tiles x (8 MFMA + 64 min3) ----
#pragma unroll
    for (int t = 0; t < 8; ++t) {
        const half8 af = __builtin_bit_cast(half8, tiles[t]);
#pragma unroll
        for (int qf = 0; qf < 8; ++qf) {
            const f32x16 dd = __builtin_amdgcn_mfma_f32_32x32x16_f16(
                af, bfrag[qf], cz, 0, 0, 0);
            acc[qf] = min16(dd, acc[qf]);
        }
    }

    // ---- epilogue: merge row-halves, one atomicMin per query ----
#pragma unroll
    for (int qf = 0; qf < 8; ++qf) {
        float v = acc[qf];
        v = fminf(v, __shfl_xor(v, 32));
        if (lane < 32)
            atomicMin(&keys[qbase + qf * 32 + n32], enc(v));
    }
}

// ---------------------------------------------------------------------------
// Final kernel: 512 blocks x 256, dir block-uniform. Decode per-query min,
// block-reduce sum, one atomicAdd per block into out[dir].
// ---------------------------------------------------------------------------
__global__ __launch_bounds__(256) void chamfer_final_atomic(
    const unsigned* __restrict__ keys, float* __restrict__ out)
{
    const int dir = blockIdx.x >> 8;                       // block-uniform
    const int qi  = ((blockIdx.x & 255) << 8) + threadIdx.x;
    const int q   = (dir << 16) + qi;

    float d = dec(keys[q]);

    for (int off = 32; off > 0; off >>= 1)
        d += __shfl_down(d, off);

    __shared__ float wsum[4];
    const int lane = threadIdx.x & 63;
    const int wv   = threadIdx.x >> 6;
    if (lane == 0) wsum[wv] = d;
    __syncthreads();
    if (threadIdx.x == 0) {
        float s = wsum[0] + wsum[1] + wsum[2] + wsum[3];
        atomicAdd(&out[dir], s * (1.0f / (float)TOTALP));
    }
}

// ---------------------------------------------------------------------------
// Fallback for tiny workspace: direct 7-op kernel, no ws needed.
// ---------------------------------------------------------------------------
__global__ void zero_out_kernel(float* __restrict__ out)
{
    if (threadIdx.x == 0) { out[0] = 0.0f; out[1] = 0.0f; }
}

__global__ __launch_bounds__(256) void chamfer_raw_kernel(
    const float* __restrict__ xyz1, const float* __restrict__ xyz2,
    float* __restrict__ out)
{
    const int blk = blockIdx.x;
    const int dir = blk >> 8;
    const int idx = blk & 255;
    const int b   = idx >> 4;
    const int n0  = (idx & 15) << 8;

    const float* __restrict__ own = (dir == 0 ? xyz1 : xyz2) + (size_t)b * NPTS * 3;
    const float* __restrict__ opp = (dir == 0 ? xyz2 : xyz1) + (size_t)b * NPTS * 3;

    const int n = n0 + threadIdx.x;
    const float ax = own[3 * n + 0];
    const float ay = own[3 * n + 1];
    const float az = own[3 * n + 2];

    float best = FLT_MAX;
    for (int m = 0; m < NPTS; m += 4) {
#pragma unroll
        for (int u = 0; u < 4; ++u) {
            const float px = opp[3 * (m + u) + 0];
            const float py = opp[3 * (m + u) + 1];
            const float pz = opp[3 * (m + u) + 2];
            const float dx = px - ax, dy = py - ay, dz = pz - az;
            float d = dx * dx;
            d = fmaf(dy, dy, d);
            d = fmaf(dz, dz, d);
            best = fminf(best, d);
        }
    }

    float d = best;
    for (int off = 32; off > 0; off >>= 1)
        d += __shfl_down(d, off);

    __shared__ float wsum[4];
    const int lane = threadIdx.x & 63;
    const int wv   = threadIdx.x >> 6;
    if (lane == 0) wsum[wv] = d;
    __syncthreads();
    if (threadIdx.x == 0) {
        float s = wsum[0] + wsum[1] + wsum[2] + wsum[3];
        atomicAdd(&out[dir], s * (1.0f / (float)TOTALP));
    }
}

// ---------------------------------------------------------------------------
extern "C" void kernel_launch(void* const* d_in, const int* in_sizes, int n_in,
                              void* d_out, int out_size, void* d_ws, size_t ws_size,
                              hipStream_t stream)
{
    const float* xyz1 = (const float*)d_in[0];
    const float* xyz2 = (const float*)d_in[1];
    float* out = (float*)d_out;

    const size_t keys_bytes  = (size_t)NQ * sizeof(unsigned);   // 512 KiB
    const size_t packQ_bytes = (size_t)NQ * sizeof(uint4);      // 2 MiB
    const size_t plane_bytes = (size_t)2 * NQ * sizeof(uint4);  // 4 MiB

    if (ws_size >= keys_bytes + packQ_bytes + plane_bytes) {    // 6.5 MiB
        unsigned* keys   = (unsigned*)d_ws;
        uint4*    packQ  = (uint4*)((char*)d_ws + keys_bytes);
        uint4*    planes = (uint4*)((char*)d_ws + keys_bytes + packQ_bytes);

        prep_kernel<<<NQ / 256, 256, 0, stream>>>(xyz1, xyz2, packQ, planes, keys, out);
        // 2048 blocks: dir(2) x b(16) x qc(4) x ch(16) -> 8 blocks/CU
        chamfer_q8<<<2048, 256, 0, stream>>>(packQ, planes, keys);
        chamfer_final_atomic<<<NQ / 256, 256, 0, stream>>>(keys, out);
    } else {
        zero_out_kernel<<<1, 64, 0, stream>>>(out);
        chamfer_raw_kernel<<<512, 256, 0, stream>>>(xyz1, xyz2, out);
    }
}

// Round 14
// 87.474 us; speedup vs baseline: 3.8673x; 3.8673x over previous
//
#include <hip/hip_runtime.h>
#include <float.h>

// Problem constants (B=16, N=M=4096, fp32, 3-D points)
#define BATCH  16
#define NPTS   4096
#define TOTALP (BATCH * NPTS)      // 65536 points per set
#define NQ     (2 * TOTALP)       // 131072 point slots (both sets)

typedef _Float16 half8  __attribute__((ext_vector_type(8)));
typedef float    f32x16 __attribute__((ext_vector_type(16)));

#define ONE2 0x3C003C00u          // two packed f16 1.0

// Order-preserving float->uint encode (unsigned compare == float compare).
__device__ __forceinline__ unsigned enc(float f)
{
    unsigned b = __float_as_uint(f);
    return (b & 0x80000000u) ? ~b : (b | 0x80000000u);
}
__device__ __forceinline__ float dec(unsigned k)
{
    return (k & 0x80000000u) ? __uint_as_float(k & 0x7FFFFFFFu)
                             : __uint_as_float(~k);
}

__device__ __forceinline__ unsigned pk(_Float16 lo, _Float16 hi)
{
    const unsigned a = (unsigned)__builtin_bit_cast(unsigned short, lo);
    const unsigned b = (unsigned)__builtin_bit_cast(unsigned short, hi);
    return a | (b << 16);
}

// In-register min of 16 MFMA outputs + running acc: 8 x v_min3_f32.
__device__ __forceinline__ float min16(const f32x16& d, float acc)
{
    const float m1 = fminf(fminf(d[0],  d[1]),  d[2]);
    const float m2 = fminf(fminf(d[3],  d[4]),  d[5]);
    const float m3 = fminf(fminf(d[6],  d[7]),  d[8]);
    const float m4 = fminf(fminf(d[9],  d[10]), d[11]);
    const float m5 = fminf(fminf(d[12], d[13]), d[14]);
    const float m6 = fminf(fminf(m1, m2), m3);
    const float m7 = fminf(fminf(m4, m5), d[15]);
    return fminf(fminf(m6, m7), acc);
}

// ---------------------------------------------------------------------------
// Prep kernel (512 blocks x 256): for every point i of both sets, write
//   packQ[i]   query record (u = -2x), minimal 16 B; B-frag halves are
//              {d.x,d.y,d.z,d.x} / {d.y,d.z,d.w,1|1} -> zero shuffling
//   planes[0][i] / planes[1][i]  opp record pre-expanded in MFMA A-frag
//              K-half layout -> main kernel streams them coalesced, no LDS
// Also inits keys[i] = +inf-key and out[0..1] = 0 (poisoned 0xAA).
// One K=16 f16 dot of (A-rec, B-rec) = ||x - p||^2 exactly (R8-R12 absmax~0).
// ---------------------------------------------------------------------------
__global__ __launch_bounds__(256) void prep_kernel(
    const float* __restrict__ xyz1, const float* __restrict__ xyz2,
    uint4* __restrict__ packQ, uint4* __restrict__ planes,
    unsigned* __restrict__ keys, float* __restrict__ out)
{
    const int i = blockIdx.x * 256 + threadIdx.x;    // 0..131071
    if (i == 0) { out[0] = 0.0f; out[1] = 0.0f; }
    keys[i] = 0xFFFFFFFFu;

    const float* src = (i < TOTALP) ? xyz1 : xyz2;
    const int p = i & (TOTALP - 1);
    const float x = src[3 * p + 0];
    const float y = src[3 * p + 1];
    const float z = src[3 * p + 2];
    const float sq = x * x + y * y + z * z;
    const _Float16 sh = (_Float16)sq;
    const _Float16 sl = (_Float16)(sq - (float)sh);

    // Opp-role A-fragment halves (v = x):
    //   half0 k0-7:  vxh vyh vzh vxh vyh vzh vxl vyl
    //   half1 k8-15: vzl vxl vyl vzl 1 1 sh sl
    const _Float16 vxh = (_Float16)x, vyh = (_Float16)y, vzh = (_Float16)z;
    const _Float16 vxl = (_Float16)(x - (float)vxh);
    const _Float16 vyl = (_Float16)(y - (float)vyh);
    const _Float16 vzl = (_Float16)(z - (float)vzh);
    planes[i]      = make_uint4(pk(vxh, vyh), pk(vzh, vxh),
                                pk(vyh, vzh), pk(vxl, vyl));
    planes[NQ + i] = make_uint4(pk(vzl, vxl), pk(vyl, vzl),
                                ONE2,         pk(sh, sl));

    // Query-role record (u = -2x), minimal:
    const float ux = -2.0f * x, uy = -2.0f * y, uz = -2.0f * z;
    const _Float16 uxh = (_Float16)ux, uyh = (_Float16)uy, uzh = (_Float16)uz;
    const _Float16 uxl = (_Float16)(ux - (float)uxh);
    const _Float16 uyl = (_Float16)(uy - (float)uyh);
    const _Float16 uzl = (_Float16)(uz - (float)uzh);
    packQ[i] = make_uint4(pk(uxh, uyh), pk(uzh, uxl), pk(uyl, uzl), pk(sh, sl));
}

// ---------------------------------------------------------------------------
// Streaming MFMA chamfer (R11 structure + depth-3 prefetch, spill-proof).
// A = opp points streamed from global (coalesced b128; one wave-load brings
// both K-halves of a 32-rec tile: lanes 0-31 plane0, lanes 32-63 plane1 =
// exactly the A-frag layout). B = 4 query frags in registers.
//   blk = ((dir*16 + b)*8 + qc)*4 + ch     (ALL selectors block-uniform)
//   Block: 512 queries (4 waves x 4 frags x 32) x 1024 opp pts (32 tiles).
//   Grid: 2 x 16 x 8 x 4 = 1024 blocks; __launch_bounds__(256,4) caps VGPR
//   at 128 (R13 lesson: batch prefetch + wide unroll -> 256 VGPR + spills).
// Rolling 3-tile register buffer: load for tile t+3 issues ~240 cyc before
// use -> covers ~200 cyc L2 latency (R12 lesson: depth 0/1 is latency-bound).
// D layout: col(query)=lane&31, row(opp)->16 regs => min16 in-register;
// epilogue: shfl_xor(32) merge + one atomicMin per query. No LDS/barriers.
// ---------------------------------------------------------------------------
__global__ __launch_bounds__(256, 4) void chamfer_stream(
    const uint4* __restrict__ packQ, const uint4* __restrict__ planes,
    unsigned* __restrict__ keys)
{
    const int blk = blockIdx.x;
    const int ch  = blk & 3;
    const int qc  = (blk >> 2) & 7;
    const int b   = (blk >> 5) & 15;
    const int dir = blk >> 9;                    // block-uniform

    const int lane = threadIdx.x & 63;
    const int wv   = threadIdx.x >> 6;
    const int n32  = lane & 31;
    const int half = lane >> 5;

    // ---- 4 query B-fragments (zero-shuffle assembly) ----
    const int qbase = dir * TOTALP + b * NPTS + qc * 512 + wv * 128;
    half8 bfrag[4];
#pragma unroll
    for (int qf = 0; qf < 4; ++qf) {
        const uint4 d = packQ[qbase + qf * 32 + n32];
        const uint4 u = half ? make_uint4(d.y, d.z, d.w, ONE2)
                             : make_uint4(d.x, d.y, d.z, d.x);
        bfrag[qf] = __builtin_bit_cast(half8, u);
    }

    float acc[4];
#pragma unroll
    for (int qf = 0; qf < 4; ++qf) acc[qf] = FLT_MAX;

    f32x16 cz;
#pragma unroll
    for (int r = 0; r < 16; ++r) cz[r] = 0.0f;

    // ---- opp stream: 32 tiles, rolling 3-deep register prefetch ----
    const uint4* __restrict__ ap =
        planes + (size_t)half * NQ + (dir ^ 1) * TOTALP + b * NPTS + ch * 1024;

    uint4 t0 = ap[0 * 32 + n32];
    uint4 t1 = ap[1 * 32 + n32];
    uint4 t2 = ap[2 * 32 + n32];

    for (int t = 0; t < 32; ++t) {
        const uint4 tn = ap[(((t + 3) & 31) * 32) + n32];   // depth-3 prefetch
        const half8 af = __builtin_bit_cast(half8, t0);
#pragma unroll
        for (int qf = 0; qf < 4; ++qf) {
            const f32x16 dd = __builtin_amdgcn_mfma_f32_32x32x16_f16(
                af, bfrag[qf], cz, 0, 0, 0);
            acc[qf] = min16(dd, acc[qf]);
        }
        t0 = t1; t1 = t2; t2 = tn;
    }

    // ---- epilogue: merge row-halves, one atomicMin per query ----
#pragma unroll
    for (int qf = 0; qf < 4; ++qf) {
        float v = acc[qf];
        v = fminf(v, __shfl_xor(v, 32));
        if (lane < 32)
            atomicMin(&keys[qbase + qf * 32 + n32], enc(v));
    }
}

// ---------------------------------------------------------------------------
// Final kernel: 512 blocks x 256, dir block-uniform. Decode per-query min,
// block-reduce sum, one atomicAdd per block into out[dir].
// ---------------------------------------------------------------------------
__global__ __launch_bounds__(256) void chamfer_final_atomic(
    const unsigned* __restrict__ keys, float* __restrict__ out)
{
    const int dir = blockIdx.x >> 8;                       // block-uniform
    const int qi  = ((blockIdx.x & 255) << 8) + threadIdx.x;
    const int q   = (dir << 16) + qi;

    float d = dec(keys[q]);

    for (int off = 32; off > 0; off >>= 1)
        d += __shfl_down(d, off);

    __shared__ float wsum[4];
    const int lane = threadIdx.x & 63;
    const int wv   = threadIdx.x >> 6;
    if (lane == 0) wsum[wv] = d;
    __syncthreads();
    if (threadIdx.x == 0) {
        float s = wsum[0] + wsum[1] + wsum[2] + wsum[3];
        atomicAdd(&out[dir], s * (1.0f / (float)TOTALP));
    }
}

// ---------------------------------------------------------------------------
// Fallback for tiny workspace: direct 7-op kernel, no ws needed.
// ---------------------------------------------------------------------------
__global__ void zero_out_kernel(float* __restrict__ out)
{
    if (threadIdx.x == 0) { out[0] = 0.0f; out[1] = 0.0f; }
}

__global__ __launch_bounds__(256) void chamfer_raw_kernel(
    const float* __restrict__ xyz1, const float* __restrict__ xyz2,
    float* __restrict__ out)
{
    const int blk = blockIdx.x;
    const int dir = blk >> 8;
    const int idx = blk & 255;
    const int b   = idx >> 4;
    const int n0  = (idx & 15) << 8;

    const float* __restrict__ own = (dir == 0 ? xyz1 : xyz2) + (size_t)b * NPTS * 3;
    const float* __restrict__ opp = (dir == 0 ? xyz2 : xyz1) + (size_t)b * NPTS * 3;

    const int n = n0 + threadIdx.x;
    const float ax = own[3 * n + 0];
    const float ay = own[3 * n + 1];
    const float az = own[3 * n + 2];

    float best = FLT_MAX;
    for (int m = 0; m < NPTS; m += 4) {
#pragma unroll
        for (int u = 0; u < 4; ++u) {
            const float px = opp[3 * (m + u) + 0];
            const float py = opp[3 * (m + u) + 1];
            const float pz = opp[3 * (m + u) + 2];
            const float dx = px - ax, dy = py - ay, dz = pz - az;
            float d = dx * dx;
            d = fmaf(dy, dy, d);
            d = fmaf(dz, dz, d);
            best = fminf(best, d);
        }
    }

    float d = best;
    for (int off = 32; off > 0; off >>= 1)
        d += __shfl_down(d, off);

    __shared__ float wsum[4];
    const int lane = threadIdx.x & 63;
    const int wv   = threadIdx.x >> 6;
    if (lane == 0) wsum[wv] = d;
    __syncthreads();
    if (threadIdx.x == 0) {
        float s = wsum[0] + wsum[1] + wsum[2] + wsum[3];
        atomicAdd(&out[dir], s * (1.0f / (float)TOTALP));
    }
}

// ---------------------------------------------------------------------------
extern "C" void kernel_launch(void* const* d_in, const int* in_sizes, int n_in,
                              void* d_out, int out_size, void* d_ws, size_t ws_size,
                              hipStream_t stream)
{
    const float* xyz1 = (const float*)d_in[0];
    const float* xyz2 = (const float*)d_in[1];
    float* out = (float*)d_out;

    const size_t keys_bytes  = (size_t)NQ * sizeof(unsigned);   // 512 KiB
    const size_t packQ_bytes = (size_t)NQ * sizeof(uint4);      // 2 MiB
    const size_t plane_bytes = (size_t)2 * NQ * sizeof(uint4);  // 4 MiB

    if (ws_size >= keys_bytes + packQ_bytes + plane_bytes) {    // 6.5 MiB
        unsigned* keys   = (unsigned*)d_ws;
        uint4*    packQ  = (uint4*)((char*)d_ws + keys_bytes);
        uint4*    planes = (uint4*)((char*)d_ws + keys_bytes + packQ_bytes);

        prep_kernel<<<NQ / 256, 256, 0, stream>>>(xyz1, xyz2, packQ, planes, keys, out);
        // 1024 blocks: dir(2) x b(16) x qc(8) x ch(4) -> 4 blocks/CU resident
        chamfer_stream<<<1024, 256, 0, stream>>>(packQ, planes, keys);
        chamfer_final_atomic<<<NQ / 256, 256, 0, stream>>>(keys, out);
    } else {
        zero_out_kernel<<<1, 64, 0, stream>>>(out);
        chamfer_raw_kernel<<<512, 256, 0, stream>>>(xyz1, xyz2, out);
    }
}

// Round 15
// 85.967 us; speedup vs baseline: 3.9351x; 1.0175x over previous
//
#include <hip/hip_runtime.h>
#include <float.h>

// Problem constants (B=16, N=M=4096, fp32, 3-D points)
#define BATCH  16
#define NPTS   4096
#define TOTALP (BATCH * NPTS)      // 65536 points per set
#define NQ     (2 * TOTALP)       // 131072 point slots (both sets)

typedef _Float16 half8  __attribute__((ext_vector_type(8)));
typedef float    f32x16 __attribute__((ext_vector_type(16)));

#define ONE2 0x3C003C00u          // two packed f16 1.0

// Order-preserving float->uint encode (unsigned compare == float compare).
__device__ __forceinline__ unsigned enc(float f)
{
    unsigned b = __float_as_uint(f);
    return (b & 0x80000000u) ? ~b : (b | 0x80000000u);
}
__device__ __forceinline__ float dec(unsigned k)
{
    return (k & 0x80000000u) ? __uint_as_float(k & 0x7FFFFFFFu)
                             : __uint_as_float(~k);
}

__device__ __forceinline__ unsigned pk(_Float16 lo, _Float16 hi)
{
    const unsigned a = (unsigned)__builtin_bit_cast(unsigned short, lo);
    const unsigned b = (unsigned)__builtin_bit_cast(unsigned short, hi);
    return a | (b << 16);
}

// In-register min of 16 MFMA outputs + running acc: 8 x v_min3_f32.
__device__ __forceinline__ float min16(const f32x16& d, float acc)
{
    const float m1 = fminf(fminf(d[0],  d[1]),  d[2]);
    const float m2 = fminf(fminf(d[3],  d[4]),  d[5]);
    const float m3 = fminf(fminf(d[6],  d[7]),  d[8]);
    const float m4 = fminf(fminf(d[9],  d[10]), d[11]);
    const float m5 = fminf(fminf(d[12], d[13]), d[14]);
    const float m6 = fminf(fminf(m1, m2), m3);
    const float m7 = fminf(fminf(m4, m5), d[15]);
    return fminf(fminf(m6, m7), acc);
}

// ---------------------------------------------------------------------------
// Prep kernel (512 blocks x 256): for every point i of both sets, write
//   packQ[i]   query record (u = -2x), minimal 16 B; B-frag halves are
//              {d.x,d.y,d.z,d.x} / {d.y,d.z,d.w,1|1} -> zero shuffling
//   planes[0][i] / planes[1][i]  opp record pre-expanded in MFMA A-frag
//              K-half layout -> main kernel streams them coalesced, no LDS
// Also inits keys[i] = +inf-key and out[0..1] = 0 (poisoned 0xAA).
// One K=16 f16 dot of (A-rec, B-rec) = ||x - p||^2 exactly (R8-R14 absmax=0).
// ---------------------------------------------------------------------------
__global__ __launch_bounds__(256) void prep_kernel(
    const float* __restrict__ xyz1, const float* __restrict__ xyz2,
    uint4* __restrict__ packQ, uint4* __restrict__ planes,
    unsigned* __restrict__ keys, float* __restrict__ out)
{
    const int i = blockIdx.x * 256 + threadIdx.x;    // 0..131071
    if (i == 0) { out[0] = 0.0f; out[1] = 0.0f; }
    keys[i] = 0xFFFFFFFFu;

    const float* src = (i < TOTALP) ? xyz1 : xyz2;
    const int p = i & (TOTALP - 1);
    const float x = src[3 * p + 0];
    const float y = src[3 * p + 1];
    const float z = src[3 * p + 2];
    const float sq = x * x + y * y + z * z;
    const _Float16 sh = (_Float16)sq;
    const _Float16 sl = (_Float16)(sq - (float)sh);

    // Opp-role A-fragment halves (v = x):
    //   half0 k0-7:  vxh vyh vzh vxh vyh vzh vxl vyl
    //   half1 k8-15: vzl vxl vyl vzl 1 1 sh sl
    const _Float16 vxh = (_Float16)x, vyh = (_Float16)y, vzh = (_Float16)z;
    const _Float16 vxl = (_Float16)(x - (float)vxh);
    const _Float16 vyl = (_Float16)(y - (float)vyh);
    const _Float16 vzl = (_Float16)(z - (float)vzh);
    planes[i]      = make_uint4(pk(vxh, vyh), pk(vzh, vxh),
                                pk(vyh, vzh), pk(vxl, vyl));
    planes[NQ + i] = make_uint4(pk(vzl, vxl), pk(vyl, vzl),
                                ONE2,         pk(sh, sl));

    // Query-role record (u = -2x), minimal:
    const float ux = -2.0f * x, uy = -2.0f * y, uz = -2.0f * z;
    const _Float16 uxh = (_Float16)ux, uyh = (_Float16)uy, uzh = (_Float16)uz;
    const _Float16 uxl = (_Float16)(ux - (float)uxh);
    const _Float16 uyl = (_Float16)(uy - (float)uyh);
    const _Float16 uzl = (_Float16)(uz - (float)uzh);
    packQ[i] = make_uint4(pk(uxh, uyh), pk(uzh, uxl), pk(uyl, uzl), pk(sh, sl));
}

// ---------------------------------------------------------------------------
// Streaming MFMA chamfer (R14 winner + depth-4 prefetch + finer grid).
// A = opp points streamed from global (coalesced b128; lanes 0-31 plane0,
// lanes 32-63 plane1 = exactly the A-frag layout). B = 4 query frags in regs.
//   blk = ((dir*16 + b)*8 + qc)*8 + ch     (ALL selectors block-uniform)
//   Block: 512 queries (4 waves x 4 frags x 32) x 512 opp pts (16 tiles).
//   Grid: 2 x 16 x 8 x 8 = 2048 blocks -> 8 blocks/CU nominal (VGPR caps
//   residency at 16 waves/CU); __launch_bounds__(256,4) keeps VGPR <= 128
//   (R13 lesson: wide unroll + batch prefetch -> 256 VGPR + scratch spills).
// Rolling 4-tile register prefetch: load t+4 issues ~400 cyc before use ->
// covers L1/L2 latency fully (R12: depth 0/1 latency-bound; R14: depth 3 ok).
// D layout: col(query)=lane&31, row(opp)->16 regs => min16 in-register;
// epilogue: shfl_xor(32) merge + one atomicMin per query. No LDS/barriers.
// ---------------------------------------------------------------------------
__global__ __launch_bounds__(256, 4) void chamfer_stream(
    const uint4* __restrict__ packQ, const uint4* __restrict__ planes,
    unsigned* __restrict__ keys)
{
    const int blk = blockIdx.x;
    const int ch  = blk & 7;
    const int qc  = (blk >> 3) & 7;
    const int b   = (blk >> 6) & 15;
    const int dir = blk >> 10;                   // block-uniform

    const int lane = threadIdx.x & 63;
    const int wv   = threadIdx.x >> 6;
    const int n32  = lane & 31;
    const int half = lane >> 5;

    // ---- 4 query B-fragments (zero-shuffle assembly) ----
    const int qbase = dir * TOTALP + b * NPTS + qc * 512 + wv * 128;
    half8 bfrag[4];
#pragma unroll
    for (int qf = 0; qf < 4; ++qf) {
        const uint4 d = packQ[qbase + qf * 32 + n32];
        const uint4 u = half ? make_uint4(d.y, d.z, d.w, ONE2)
                             : make_uint4(d.x, d.y, d.z, d.x);
        bfrag[qf] = __builtin_bit_cast(half8, u);
    }

    float acc[4];
#pragma unroll
    for (int qf = 0; qf < 4; ++qf) acc[qf] = FLT_MAX;

    f32x16 cz;
#pragma unroll
    for (int r = 0; r < 16; ++r) cz[r] = 0.0f;

    // ---- opp stream: 16 tiles, rolling 4-deep register prefetch ----
    const uint4* __restrict__ ap =
        planes + (size_t)half * NQ + (dir ^ 1) * TOTALP + b * NPTS + ch * 512;

    uint4 t0 = ap[0 * 32 + n32];
    uint4 t1 = ap[1 * 32 + n32];
    uint4 t2 = ap[2 * 32 + n32];
    uint4 t3 = ap[3 * 32 + n32];

    for (int t = 0; t < 16; ++t) {
        const uint4 tn = ap[(((t + 4) & 15) * 32) + n32];   // depth-4 prefetch
        const half8 af = __builtin_bit_cast(half8, t0);
#pragma unroll
        for (int qf = 0; qf < 4; ++qf) {
            const f32x16 dd = __builtin_amdgcn_mfma_f32_32x32x16_f16(
                af, bfrag[qf], cz, 0, 0, 0);
            acc[qf] = min16(dd, acc[qf]);
        }
        t0 = t1; t1 = t2; t2 = t3; t3 = tn;
    }

    // ---- epilogue: merge row-halves, one atomicMin per query ----
#pragma unroll
    for (int qf = 0; qf < 4; ++qf) {
        float v = acc[qf];
        v = fminf(v, __shfl_xor(v, 32));
        if (lane < 32)
            atomicMin(&keys[qbase + qf * 32 + n32], enc(v));
    }
}

// ---------------------------------------------------------------------------
// Final kernel: 256 blocks x 256, 2 queries/thread, dir block-uniform.
// Decode per-query mins, block-reduce sum, one atomicAdd per block.
// ---------------------------------------------------------------------------
__global__ __launch_bounds__(256) void chamfer_final_atomic(
    const unsigned* __restrict__ keys, float* __restrict__ out)
{
    const int q0  = blockIdx.x * 512 + threadIdx.x;   // q0 and q0+256
    const int dir = q0 >> 16;                          // block-uniform

    float d = dec(keys[q0]) + dec(keys[q0 + 256]);

    for (int off = 32; off > 0; off >>= 1)
        d += __shfl_down(d, off);

    __shared__ float wsum[4];
    const int lane = threadIdx.x & 63;
    const int wv   = threadIdx.x >> 6;
    if (lane == 0) wsum[wv] = d;
    __syncthreads();
    if (threadIdx.x == 0) {
        float s = wsum[0] + wsum[1] + wsum[2] + wsum[3];
        atomicAdd(&out[dir], s * (1.0f / (float)TOTALP));
    }
}

// ---------------------------------------------------------------------------
// Fallback for tiny workspace: direct 7-op kernel, no ws needed.
// ---------------------------------------------------------------------------
__global__ void zero_out_kernel(float* __restrict__ out)
{
    if (threadIdx.x == 0) { out[0] = 0.0f; out[1] = 0.0f; }
}

__global__ __launch_bounds__(256) void chamfer_raw_kernel(
    const float* __restrict__ xyz1, const float* __restrict__ xyz2,
    float* __restrict__ out)
{
    const int blk = blockIdx.x;
    const int dir = blk >> 8;
    const int idx = blk & 255;
    const int b   = idx >> 4;
    const int n0  = (idx & 15) << 8;

    const float* __restrict__ own = (dir == 0 ? xyz1 : xyz2) + (size_t)b * NPTS * 3;
    const float* __restrict__ opp = (dir == 0 ? xyz2 : xyz1) + (size_t)b * NPTS * 3;

    const int n = n0 + threadIdx.x;
    const float ax = own[3 * n + 0];
    const float ay = own[3 * n + 1];
    const float az = own[3 * n + 2];

    float best = FLT_MAX;
    for (int m = 0; m < NPTS; m += 4) {
#pragma unroll
        for (int u = 0; u < 4; ++u) {
            const float px = opp[3 * (m + u) + 0];
            const float py = opp[3 * (m + u) + 1];
            const float pz = opp[3 * (m + u) + 2];
            const float dx = px - ax, dy = py - ay, dz = pz - az;
            float d = dx * dx;
            d = fmaf(dy, dy, d);
            d = fmaf(dz, dz, d);
            best = fminf(best, d);
        }
    }

    float d = best;
    for (int off = 32; off > 0; off >>= 1)
        d += __shfl_down(d, off);

    __shared__ float wsum[4];
    const int lane = threadIdx.x & 63;
    const int wv   = threadIdx.x >> 6;
    if (lane == 0) wsum[wv] = d;
    __syncthreads();
    if (threadIdx.x == 0) {
        float s = wsum[0] + wsum[1] + wsum[2] + wsum[3];
        atomicAdd(&out[dir], s * (1.0f / (float)TOTALP));
    }
}

// ---------------------------------------------------------------------------
extern "C" void kernel_launch(void* const* d_in, const int* in_sizes, int n_in,
                              void* d_out, int out_size, void* d_ws, size_t ws_size,
                              hipStream_t stream)
{
    const float* xyz1 = (const float*)d_in[0];
    const float* xyz2 = (const float*)d_in[1];
    float* out = (float*)d_out;

    const size_t keys_bytes  = (size_t)NQ * sizeof(unsigned);   // 512 KiB
    const size_t packQ_bytes = (size_t)NQ * sizeof(uint4);      // 2 MiB
    const size_t plane_bytes = (size_t)2 * NQ * sizeof(uint4);  // 4 MiB

    if (ws_size >= keys_bytes + packQ_bytes + plane_bytes) {    // 6.5 MiB
        unsigned* keys   = (unsigned*)d_ws;
        uint4*    packQ  = (uint4*)((char*)d_ws + keys_bytes);
        uint4*    planes = (uint4*)((char*)d_ws + keys_bytes + packQ_bytes);

        prep_kernel<<<NQ / 256, 256, 0, stream>>>(xyz1, xyz2, packQ, planes, keys, out);
        // 2048 blocks: dir(2) x b(16) x qc(8) x ch(8) -> 8 blocks/CU nominal
        chamfer_stream<<<2048, 256, 0, stream>>>(packQ, planes, keys);
        chamfer_final_atomic<<<NQ / 512, 256, 0, stream>>>(keys, out);
    } else {
        zero_out_kernel<<<1, 64, 0, stream>>>(out);
        chamfer_raw_kernel<<<512, 256, 0, stream>>>(xyz1, xyz2, out);
    }
}